// Round 3
// baseline (471.876 us; speedup 1.0000x reference)
//
#include <hip/hip_runtime.h>

// HomologicalConnectivityLoss: adj (8192x8192 fp32, bit-exact symmetric).
// loss = (n_comp-1)^2 + max(0, n_edges - N + n_comp)^2
//
// Ladder:
//  R1 767us: fused global union-find (pointer-chase poison).
//  R2 1553us: per-edge global atomicAdd append + global union-find.
//  R3 437us: LDS edge staging + single-block LDS union-find.
//  R4 415us: SV min-label propagation in LDS; scan 4-loads-in-flight.
//  R5 404us: scan 9-deep MLP (row-pair virtual index space, no tail loop);
//            label 8-deep edge prefetch.
//            POST-MORTEM: top-5 dispatches are all harness ws-poison fills
//            (2 x 1GiB @ 84% HBM peak ~ 321us, inside the timed region).
//            Controllable kernel budget is only ~83us of the 404.
//  R6 (this): label keeps the edge list in REGISTERS across rounds:
//            512 thr x 160 static u32 slots (81920 cap >= m~77K, 17 sigma).
//            Invalid slots encode edge (0,0) = natural no-op -> zero
//            per-round predication, zero per-round global traffic.
//            3 pointer-jump shortcut passes per round. Fallback streaming
//            path for m > 81920 (never taken in practice).
//
// Workspace (ints): ws[0]=lower-edge count, ws[1]=diag count,
// ws[2..] = edge buffer (u32 encoded (r<<13)|j, r>j).

#define NN 8192
#define SCAN_LDS_CAP 2048   // expected ~19 edges/block; huge margin
#define LBL_THREADS 512
#define EPT 160             // edges per thread held in registers
#define REGCAP (LBL_THREADS * EPT)

__global__ __launch_bounds__(64) void init_kernel(int* counters) {
    if (threadIdx.x < 2) counters[threadIdx.x] = 0;
}

// Block b processes rows b and NN-1-b (cols 0..r): balanced triangle scan.
// The two rows form one virtual float4 index space of 2049-2050 entries ->
// exactly 9 per thread at 256 threads. All 9 loads issued back-to-back
// (independent, predicated) before any processing: 9-deep MLP per thread.
__global__ __launch_bounds__(256) void scan_kernel(const float* __restrict__ adj,
                                                   int* __restrict__ counters,
                                                   unsigned int* __restrict__ ebuf,
                                                   int cap) {
    __shared__ int lds_n;
    __shared__ int lds_base;
    __shared__ unsigned int lds_e[SCAN_LDS_CAP];
    if (threadIdx.x == 0) lds_n = 0;
    __syncthreads();

    int b = blockIdx.x;
    int ra = b;
    int rb = NN - 1 - b;
    int nfa = (ra + 4) >> 2;          // ceil((ra+1)/4)
    int nfb = (rb + 4) >> 2;
    int tot = nfa + nfb;              // always 2049 or 2050 (<= 9*256)

    int t = threadIdx.x;
    int c1 = 0;                       // diagonal positives

    float4 v[9];
    int   rr[9];
    int   gg[9];
    bool  ok[9];

    // issue phase: 9 independent loads in flight
    #pragma unroll
    for (int k = 0; k < 9; ++k) {
        int vg = t + (k << 8);
        ok[k] = vg < tot;
        bool inA = vg < nfa;
        int r = inA ? ra : rb;
        int g = inA ? vg : vg - nfa;
        rr[k] = r;
        gg[k] = g;
        if (ok[k]) v[k] = ((const float4*)(adj + (size_t)r * NN))[g];
    }

    // process phase
    #pragma unroll
    for (int k = 0; k < 9; ++k) {
        if (!ok[k]) continue;
        int r  = rr[k];
        int j0 = gg[k] << 2;
        float vv[4] = {v[k].x, v[k].y, v[k].z, v[k].w};
        #pragma unroll
        for (int c = 0; c < 4; ++c) {
            int j = j0 + c;
            bool pos = vv[c] > 0.0f;
            if (pos && j < r) {
                int kk = atomicAdd(&lds_n, 1);   // LDS atomic: CU-local
                unsigned int e = ((unsigned)r << 13) | (unsigned)j;
                if (kk < SCAN_LDS_CAP) lds_e[kk] = e;
                else {  // never taken in practice; correctness fallback
                    int gk = atomicAdd(counters, 1);
                    if (gk < cap) ebuf[gk] = e;
                }
            }
            c1 += (pos && j == r) ? 1 : 0;
        }
    }

    // diag count: wave reduce, one atomic per wave
    #pragma unroll
    for (int off = 32; off > 0; off >>= 1) c1 += __shfl_down(c1, off, 64);
    if ((t & 63) == 0 && c1) atomicAdd(counters + 1, c1);

    __syncthreads();
    int n = lds_n < SCAN_LDS_CAP ? lds_n : SCAN_LDS_CAP;
    if (t == 0) lds_base = atomicAdd(counters, n);  // 1 global atomic per block
    __syncthreads();
    int base = lds_base;
    for (int k = t; k < n; k += 256) {
        int idx = base + k;
        if (idx < cap) ebuf[idx] = lds_e[k];
    }
}

// Single block: min-label propagation, labels in LDS, EDGES IN REGISTERS.
// Load phase: each thread pulls up to EPT=160 edges into a statically
// indexed register array (coalesced, one pass). Slots past m hold 0 =
// edge (0,0): lab[0]==lab[0] -> permanent no-op, so rounds need no
// predication and no global loads at all.
// Relax: 2 independent LDS atomicMins per edge (monotone, benign races).
// Shortcut: 3 pointer-jumping passes (lab[i]=lab[lab[i]]; labels are node
// indices of the SAME component and only decrease).
// Fixpoint: exactly one node per component keeps lab[i]==i (the min).
__global__ __launch_bounds__(LBL_THREADS) void label_final_kernel(
        const unsigned int* __restrict__ ebuf,
        const int* __restrict__ counters,
        int cap, float* __restrict__ out) {
    __shared__ int lab[NN];          // 32 KB
    __shared__ int changed;
    __shared__ int wsum[LBL_THREADS / 64];
    int tid = threadIdx.x;
    for (int i = tid; i < NN; i += LBL_THREADS) lab[i] = i;

    int total_lower = counters[0];
    int m = total_lower < cap ? total_lower : cap;

    // one-time edge load into registers (coalesced; invalid -> 0 = no-op)
    unsigned int e[EPT];
    #pragma unroll
    for (int q = 0; q < EPT; ++q) {
        int idx = tid + q * LBL_THREADS;
        e[q] = (idx < m) ? ebuf[idx] : 0u;
    }
    __syncthreads();

    for (;;) {
        if (tid == 0) changed = 0;
        __syncthreads();

        // relax: all edges from registers, no predication
        #pragma unroll
        for (int q = 0; q < EPT; ++q) {
            int r = (int)(e[q] >> 13);
            int j = (int)(e[q] & (NN - 1));
            int lr = lab[r];
            int lj = lab[j];
            if (lj < lr) {
                if (atomicMin(&lab[r], lj) > lj) changed = 1;
            } else if (lr < lj) {
                if (atomicMin(&lab[j], lr) > lr) changed = 1;
            }
        }
        // fallback for m > REGCAP (never taken in practice)
        for (int idx = REGCAP + tid; idx < m; idx += LBL_THREADS) {
            unsigned int eg = ebuf[idx];
            int r = (int)(eg >> 13);
            int j = (int)(eg & (NN - 1));
            int lr = lab[r];
            int lj = lab[j];
            if (lj < lr) {
                if (atomicMin(&lab[r], lj) > lj) changed = 1;
            } else if (lr < lj) {
                if (atomicMin(&lab[j], lr) > lr) changed = 1;
            }
        }
        __syncthreads();

        // shortcut: three pointer-jumping passes (monotone, benign races)
        #pragma unroll
        for (int s = 0; s < 3; ++s) {
            for (int i = tid; i < NN; i += LBL_THREADS) {
                int l = lab[i];
                int ll = lab[l];
                if (ll < l) { lab[i] = ll; changed = 1; }
            }
        }
        __syncthreads();

        if (changed == 0) break;   // uniform decision (post-barrier read)
        __syncthreads();           // protect next round's reset vs this read
    }

    // count self-labeled nodes = component count
    int cnt = 0;
    for (int i = tid; i < NN; i += LBL_THREADS) cnt += (lab[i] == i) ? 1 : 0;
    #pragma unroll
    for (int off = 32; off > 0; off >>= 1) cnt += __shfl_down(cnt, off, 64);
    if ((tid & 63) == 0) wsum[tid >> 6] = cnt;
    __syncthreads();
    if (tid == 0) {
        int roots = 0;
        #pragma unroll
        for (int w = 0; w < LBL_THREADS / 64; ++w) roots += wsum[w];
        long long total = 2LL * (long long)total_lower + (long long)counters[1];
        long long n_edges_i = total >> 1;               // exact integer // 2
        double n_comp = (double)roots;
        double comp_loss = (n_comp - 1.0) * (n_comp - 1.0);
        double betti = (double)n_edges_i - (double)NN + n_comp;
        double cyc = betti > 0.0 ? betti : 0.0;
        out[0] = (float)(comp_loss + cyc * cyc);
    }
}

extern "C" void kernel_launch(void* const* d_in, const int* in_sizes, int n_in,
                              void* d_out, int out_size, void* d_ws, size_t ws_size,
                              hipStream_t stream) {
    const float* adj = (const float*)d_in[0];
    int* ws = (int*)d_ws;
    int* counters = ws;                       // [0]=lower edges, [1]=diag
    unsigned int* ebuf = (unsigned int*)(ws + 2);
    long long cap_ll = (long long)(ws_size / 4) - 2;
    int cap = cap_ll > 0x7fffffff ? 0x7fffffff : (cap_ll < 0 ? 0 : (int)cap_ll);
    float* out = (float*)d_out;

    init_kernel<<<1, 64, 0, stream>>>(counters);
    scan_kernel<<<NN / 2, 256, 0, stream>>>(adj, counters, ebuf, cap);
    label_final_kernel<<<1, LBL_THREADS, 0, stream>>>(ebuf, counters, cap, out);
}

// Round 4
// 431.155 us; speedup vs baseline: 1.0944x; 1.0944x over previous
//
#include <hip/hip_runtime.h>

// HomologicalConnectivityLoss: adj (8192x8192 fp32, bit-exact symmetric).
// loss = (n_comp-1)^2 + max(0, n_edges - N + n_comp)^2
//
// Ladder:
//  R1 767us: fused global union-find (pointer-chase poison).
//  R2 1553us: per-edge global atomicAdd append + global union-find.
//  R3 437us: LDS edge staging + single-block LDS union-find.
//  R4 415us: SV min-label propagation in LDS; scan 4-loads-in-flight.
//  R5 404us: scan 9-deep MLP; label 8-deep edge prefetch, 1024 thr.
//            POST-MORTEM: timed region = harness ws-poison fills (~321us
//            @84% HBM peak, uncontrollable) + ~83us ours.
//  R6 472us REGRESSION: edges-in-registers at 512 thr / EPT=160:
//            ~180 VGPR -> >128-VGPR cliff -> 8 waves (was 16), and
//            per-thread round work doubled (160 vs 76 iters). Label ~108us.
//  R7 (this): register-hold retained but at 1024 thr / EPT=80:
//            ~100 VGPR -> 16 waves (= R5), per-thread work = R5 (~80),
//            zero per-round global edge traffic. 3 pointer-jump shortcut
//            passes per round. Fallback streaming path for m > 81920.
//
// Workspace (ints): ws[0]=lower-edge count, ws[1]=diag count,
// ws[2..] = edge buffer (u32 encoded (r<<13)|j, r>j).

#define NN 8192
#define SCAN_LDS_CAP 2048   // expected ~19 edges/block; huge margin
#define LBL_THREADS 1024
#define EPT 80              // edges per thread held in registers
#define REGCAP (LBL_THREADS * EPT)

__global__ __launch_bounds__(64) void init_kernel(int* counters) {
    if (threadIdx.x < 2) counters[threadIdx.x] = 0;
}

// Block b processes rows b and NN-1-b (cols 0..r): balanced triangle scan.
// The two rows form one virtual float4 index space of 2049-2050 entries ->
// exactly 9 per thread at 256 threads. All 9 loads issued back-to-back
// (independent, predicated) before any processing: 9-deep MLP per thread.
__global__ __launch_bounds__(256) void scan_kernel(const float* __restrict__ adj,
                                                   int* __restrict__ counters,
                                                   unsigned int* __restrict__ ebuf,
                                                   int cap) {
    __shared__ int lds_n;
    __shared__ int lds_base;
    __shared__ unsigned int lds_e[SCAN_LDS_CAP];
    if (threadIdx.x == 0) lds_n = 0;
    __syncthreads();

    int b = blockIdx.x;
    int ra = b;
    int rb = NN - 1 - b;
    int nfa = (ra + 4) >> 2;          // ceil((ra+1)/4)
    int nfb = (rb + 4) >> 2;
    int tot = nfa + nfb;              // always 2049 or 2050 (<= 9*256)

    int t = threadIdx.x;
    int c1 = 0;                       // diagonal positives

    float4 v[9];
    int   rr[9];
    int   gg[9];
    bool  ok[9];

    // issue phase: 9 independent loads in flight
    #pragma unroll
    for (int k = 0; k < 9; ++k) {
        int vg = t + (k << 8);
        ok[k] = vg < tot;
        bool inA = vg < nfa;
        int r = inA ? ra : rb;
        int g = inA ? vg : vg - nfa;
        rr[k] = r;
        gg[k] = g;
        if (ok[k]) v[k] = ((const float4*)(adj + (size_t)r * NN))[g];
    }

    // process phase
    #pragma unroll
    for (int k = 0; k < 9; ++k) {
        if (!ok[k]) continue;
        int r  = rr[k];
        int j0 = gg[k] << 2;
        float vv[4] = {v[k].x, v[k].y, v[k].z, v[k].w};
        #pragma unroll
        for (int c = 0; c < 4; ++c) {
            int j = j0 + c;
            bool pos = vv[c] > 0.0f;
            if (pos && j < r) {
                int kk = atomicAdd(&lds_n, 1);   // LDS atomic: CU-local
                unsigned int e = ((unsigned)r << 13) | (unsigned)j;
                if (kk < SCAN_LDS_CAP) lds_e[kk] = e;
                else {  // never taken in practice; correctness fallback
                    int gk = atomicAdd(counters, 1);
                    if (gk < cap) ebuf[gk] = e;
                }
            }
            c1 += (pos && j == r) ? 1 : 0;
        }
    }

    // diag count: wave reduce, one atomic per wave
    #pragma unroll
    for (int off = 32; off > 0; off >>= 1) c1 += __shfl_down(c1, off, 64);
    if ((t & 63) == 0 && c1) atomicAdd(counters + 1, c1);

    __syncthreads();
    int n = lds_n < SCAN_LDS_CAP ? lds_n : SCAN_LDS_CAP;
    if (t == 0) lds_base = atomicAdd(counters, n);  // 1 global atomic per block
    __syncthreads();
    int base = lds_base;
    for (int k = t; k < n; k += 256) {
        int idx = base + k;
        if (idx < cap) ebuf[idx] = lds_e[k];
    }
}

// Single block: min-label propagation, labels in LDS, EDGES IN REGISTERS.
// 1024 threads x EPT=80 slots (~100 VGPR -> 16 waves/CU, no occupancy
// cliff; per-thread round work identical to R5's streaming version).
// Slots past m hold 0 = edge (0,0): lab[0]==lab[0] -> permanent no-op,
// so rounds need no predication and zero global traffic.
// Relax: 2 independent LDS atomicMins per edge (monotone, benign races).
// Shortcut: 3 pointer-jumping passes (lab[i]=lab[lab[i]]; labels are node
// indices of the SAME component and only decrease).
// Fixpoint: exactly one node per component keeps lab[i]==i (the min).
__global__ __launch_bounds__(LBL_THREADS) void label_final_kernel(
        const unsigned int* __restrict__ ebuf,
        const int* __restrict__ counters,
        int cap, float* __restrict__ out) {
    __shared__ int lab[NN];          // 32 KB
    __shared__ int changed;
    __shared__ int wsum[LBL_THREADS / 64];
    int tid = threadIdx.x;
    for (int i = tid; i < NN; i += LBL_THREADS) lab[i] = i;

    int total_lower = counters[0];
    int m = total_lower < cap ? total_lower : cap;

    // one-time edge load into registers (coalesced; invalid -> 0 = no-op)
    unsigned int e[EPT];
    #pragma unroll
    for (int q = 0; q < EPT; ++q) {
        int idx = tid + q * LBL_THREADS;
        e[q] = (idx < m) ? ebuf[idx] : 0u;
    }
    __syncthreads();

    for (;;) {
        if (tid == 0) changed = 0;
        __syncthreads();

        // relax: all edges from registers, no predication
        #pragma unroll
        for (int q = 0; q < EPT; ++q) {
            int r = (int)(e[q] >> 13);
            int j = (int)(e[q] & (NN - 1));
            int lr = lab[r];
            int lj = lab[j];
            if (lj < lr) {
                if (atomicMin(&lab[r], lj) > lj) changed = 1;
            } else if (lr < lj) {
                if (atomicMin(&lab[j], lr) > lr) changed = 1;
            }
        }
        // fallback for m > REGCAP (never taken in practice)
        for (int idx = REGCAP + tid; idx < m; idx += LBL_THREADS) {
            unsigned int eg = ebuf[idx];
            int r = (int)(eg >> 13);
            int j = (int)(eg & (NN - 1));
            int lr = lab[r];
            int lj = lab[j];
            if (lj < lr) {
                if (atomicMin(&lab[r], lj) > lj) changed = 1;
            } else if (lr < lj) {
                if (atomicMin(&lab[j], lr) > lr) changed = 1;
            }
        }
        __syncthreads();

        // shortcut: three pointer-jumping passes (monotone, benign races)
        #pragma unroll
        for (int s = 0; s < 3; ++s) {
            for (int i = tid; i < NN; i += LBL_THREADS) {
                int l = lab[i];
                int ll = lab[l];
                if (ll < l) { lab[i] = ll; changed = 1; }
            }
        }
        __syncthreads();

        if (changed == 0) break;   // uniform decision (post-barrier read)
        __syncthreads();           // protect next round's reset vs this read
    }

    // count self-labeled nodes = component count
    int cnt = 0;
    for (int i = tid; i < NN; i += LBL_THREADS) cnt += (lab[i] == i) ? 1 : 0;
    #pragma unroll
    for (int off = 32; off > 0; off >>= 1) cnt += __shfl_down(cnt, off, 64);
    if ((tid & 63) == 0) wsum[tid >> 6] = cnt;
    __syncthreads();
    if (tid == 0) {
        int roots = 0;
        #pragma unroll
        for (int w = 0; w < LBL_THREADS / 64; ++w) roots += wsum[w];
        long long total = 2LL * (long long)total_lower + (long long)counters[1];
        long long n_edges_i = total >> 1;               // exact integer // 2
        double n_comp = (double)roots;
        double comp_loss = (n_comp - 1.0) * (n_comp - 1.0);
        double betti = (double)n_edges_i - (double)NN + n_comp;
        double cyc = betti > 0.0 ? betti : 0.0;
        out[0] = (float)(comp_loss + cyc * cyc);
    }
}

extern "C" void kernel_launch(void* const* d_in, const int* in_sizes, int n_in,
                              void* d_out, int out_size, void* d_ws, size_t ws_size,
                              hipStream_t stream) {
    const float* adj = (const float*)d_in[0];
    int* ws = (int*)d_ws;
    int* counters = ws;                       // [0]=lower edges, [1]=diag
    unsigned int* ebuf = (unsigned int*)(ws + 2);
    long long cap_ll = (long long)(ws_size / 4) - 2;
    int cap = cap_ll > 0x7fffffff ? 0x7fffffff : (cap_ll < 0 ? 0 : (int)cap_ll);
    float* out = (float*)d_out;

    init_kernel<<<1, 64, 0, stream>>>(counters);
    scan_kernel<<<NN / 2, 256, 0, stream>>>(adj, counters, ebuf, cap);
    label_final_kernel<<<1, LBL_THREADS, 0, stream>>>(ebuf, counters, cap, out);
}

// Round 5
// 391.218 us; speedup vs baseline: 1.2062x; 1.1021x over previous
//
#include <hip/hip_runtime.h>

// HomologicalConnectivityLoss: adj (8192x8192 fp32, bit-exact symmetric).
// loss = (n_comp-1)^2 + max(0, n_edges - N + n_comp)^2
//
// Ladder:
//  R1 767us: fused global union-find (pointer-chase poison).
//  R2 1553us: per-edge global atomicAdd append + global union-find.
//  R3 437us: LDS edge staging + single-block LDS union-find.
//  R4 415us: SV min-label propagation in LDS; scan 4-loads-in-flight.
//  R5 404us: scan 9-deep MLP; label streaming 8-deep prefetch, 1024 thr.
//            Model: timed region = 2x1GiB harness poison fills (~321us @84%
//            HBM peak, uncontrollable) + ~83us ours.
//  R6 472us REGRESSION: edges-in-registers, 512thr/EPT=160 (VGPR cliff +
//            2x per-thread work).
//  R7 431us REGRESSION: edges-in-registers, 1024thr/EPT=80 (occupancy
//            matched R5; still worse -> register-hold intrinsically bad;
//            streaming from L2 wins).
//  R8 (this): revert to streaming label + STAR-GROUPED relax:
//    scan: per-row LDS staging (ea/eb) so each row's edges flush
//          contiguously -> ebuf is row-run-ordered.
//    label: threads own consecutive edge chunks; per run of equal r:
//          read lab[r] once, running prefix-min mu, one deferred
//          atomicMin for r per run, conditional atomicMin per j.
//          Per-edge LDS reads 2 -> ~1.05. Prefix-min relax is >= pairwise
//          relax per round; fixpoint (no atomicMin fires) still implies
//          all edges have equal labels -> uniform label per component ->
//          exactly one self-labeled node per component.
//
// Workspace (ints): ws[0]=lower-edge count, ws[1]=diag count,
// ws[2..] = edge buffer (u32 encoded (r<<13)|j, r>j).

#define NN 8192
#define ROW_LDS_CAP 1024    // expected ~19 edges/row; Poisson max ~50
#define LBL_THREADS 1024

__global__ __launch_bounds__(64) void init_kernel(int* counters) {
    if (threadIdx.x < 2) counters[threadIdx.x] = 0;
}

// Block b processes rows b and NN-1-b (cols 0..r): balanced triangle scan.
// The two rows form one virtual float4 index space of 2049-2050 entries ->
// exactly 9 per thread at 256 threads. All 9 loads issued back-to-back
// (independent, predicated) before any processing: 9-deep MLP per thread.
// Edges staged per-row in LDS; both rows flushed contiguously with ONE
// global atomicAdd per block -> ebuf is ordered in row-runs.
__global__ __launch_bounds__(256) void scan_kernel(const float* __restrict__ adj,
                                                   int* __restrict__ counters,
                                                   unsigned int* __restrict__ ebuf,
                                                   int cap) {
    __shared__ int na, nb;
    __shared__ int lds_base;
    __shared__ unsigned int ea[ROW_LDS_CAP];
    __shared__ unsigned int eb[ROW_LDS_CAP];
    if (threadIdx.x == 0) { na = 0; nb = 0; }
    __syncthreads();

    int b = blockIdx.x;
    int ra = b;
    int rb = NN - 1 - b;
    int nfa = (ra + 4) >> 2;          // ceil((ra+1)/4)
    int nfb = (rb + 4) >> 2;
    int tot = nfa + nfb;              // always 2049 or 2050 (<= 9*256)

    int t = threadIdx.x;
    int c1 = 0;                       // diagonal positives

    float4 v[9];
    int   rr[9];
    int   gg[9];
    bool  ok[9];

    // issue phase: 9 independent loads in flight
    #pragma unroll
    for (int k = 0; k < 9; ++k) {
        int vg = t + (k << 8);
        ok[k] = vg < tot;
        bool inA = vg < nfa;
        int r = inA ? ra : rb;
        int g = inA ? vg : vg - nfa;
        rr[k] = r;
        gg[k] = g;
        if (ok[k]) v[k] = ((const float4*)(adj + (size_t)r * NN))[g];
    }

    // process phase
    #pragma unroll
    for (int k = 0; k < 9; ++k) {
        if (!ok[k]) continue;
        int r  = rr[k];
        int j0 = gg[k] << 2;
        bool isA = (r == ra);
        float vv[4] = {v[k].x, v[k].y, v[k].z, v[k].w};
        #pragma unroll
        for (int c = 0; c < 4; ++c) {
            int j = j0 + c;
            bool pos = vv[c] > 0.0f;
            if (pos && j < r) {
                unsigned int e = ((unsigned)r << 13) | (unsigned)j;
                int kk = isA ? atomicAdd(&na, 1) : atomicAdd(&nb, 1);
                if (kk < ROW_LDS_CAP) { (isA ? ea : eb)[kk] = e; }
                else {  // never taken in practice; correctness fallback
                    int gk = atomicAdd(counters, 1);
                    if (gk < cap) ebuf[gk] = e;
                }
            }
            c1 += (pos && j == r) ? 1 : 0;
        }
    }

    // diag count: wave reduce, one atomic per wave
    #pragma unroll
    for (int off = 32; off > 0; off >>= 1) c1 += __shfl_down(c1, off, 64);
    if ((t & 63) == 0 && c1) atomicAdd(counters + 1, c1);

    __syncthreads();
    int na_c = na < ROW_LDS_CAP ? na : ROW_LDS_CAP;
    int nb_c = nb < ROW_LDS_CAP ? nb : ROW_LDS_CAP;
    if (t == 0) lds_base = atomicAdd(counters, na_c + nb_c);  // 1 per block
    __syncthreads();
    int base = lds_base;
    for (int k = t; k < na_c; k += 256) {
        int idx = base + k;
        if (idx < cap) ebuf[idx] = ea[k];
    }
    for (int k = t; k < nb_c; k += 256) {
        int idx = base + na_c + k;
        if (idx < cap) ebuf[idx] = eb[k];
    }
}

// Single block: min-label propagation, labels in LDS, edges streamed from
// L2 in per-thread CONSECUTIVE chunks (row-runs preserved by the scan).
// Star relax per run of equal r: lab[r] read once, running prefix-min mu
// (>= pairwise relax strength), deferred atomicMin on r at run end,
// conditional atomicMin per j. Stale reads are sound: labels only
// decrease; a stale (older, larger) value at worst triggers a harmless
// no-op atomic or an extra round. Fixpoint: no atomicMin lowers anything
// -> every edge has equal endpoint labels -> uniform label per component
// -> exactly one node per component keeps lab[i]==i.
__global__ __launch_bounds__(LBL_THREADS) void label_final_kernel(
        const unsigned int* __restrict__ ebuf,
        const int* __restrict__ counters,
        int cap, float* __restrict__ out) {
    __shared__ int lab[NN];          // 32 KB
    __shared__ int changed;
    __shared__ int wsum[LBL_THREADS / 64];
    int tid = threadIdx.x;
    for (int i = tid; i < NN; i += LBL_THREADS) lab[i] = i;

    int total_lower = counters[0];
    int m = total_lower < cap ? total_lower : cap;
    int cchunk = (m + LBL_THREADS - 1) / LBL_THREADS;   // ~76
    int s = tid * cchunk;
    int epos = s + cchunk; if (epos > m) epos = m;
    if (s > m) s = m;

    for (;;) {
        if (tid == 0) changed = 0;
        __syncthreads();

        // star-grouped relax over this thread's consecutive chunk
        {
            int cur_r = -1, lr = 0, mu = 0;
            auto proc = [&](unsigned int eg) {
                int r = (int)(eg >> 13);
                int j = (int)(eg & (NN - 1));
                int lj = lab[j];                  // independent, issues early
                if (r != cur_r) {
                    if (cur_r >= 0 && mu < lr) {
                        if (atomicMin(&lab[cur_r], mu) > mu) changed = 1;
                    }
                    cur_r = r; lr = lab[r]; mu = lr;
                }
                if (lj < mu) mu = lj;
                else if (mu < lj) {
                    if (atomicMin(&lab[j], mu) > mu) changed = 1;
                }
            };
            int idx = s;
            for (; idx + 4 <= epos; idx += 4) {   // 4 edge loads in flight
                unsigned int e0 = ebuf[idx];
                unsigned int e1 = ebuf[idx + 1];
                unsigned int e2 = ebuf[idx + 2];
                unsigned int e3 = ebuf[idx + 3];
                proc(e0); proc(e1); proc(e2); proc(e3);
            }
            for (; idx < epos; ++idx) proc(ebuf[idx]);
            if (cur_r >= 0 && mu < lr) {
                if (atomicMin(&lab[cur_r], mu) > mu) changed = 1;
            }
        }
        __syncthreads();

        // shortcut: two pointer-jumping passes (monotone, benign races;
        // each thread owns disjoint i, so stores don't collide)
        #pragma unroll
        for (int sc = 0; sc < 2; ++sc) {
            for (int i = tid; i < NN; i += LBL_THREADS) {
                int l = lab[i];
                int ll = lab[l];
                if (ll < l) { lab[i] = ll; changed = 1; }
            }
        }
        __syncthreads();

        if (changed == 0) break;   // uniform decision (post-barrier read)
        __syncthreads();           // protect next round's reset vs this read
    }

    // count self-labeled nodes = component count
    int cnt = 0;
    for (int i = tid; i < NN; i += LBL_THREADS) cnt += (lab[i] == i) ? 1 : 0;
    #pragma unroll
    for (int off = 32; off > 0; off >>= 1) cnt += __shfl_down(cnt, off, 64);
    if ((tid & 63) == 0) wsum[tid >> 6] = cnt;
    __syncthreads();
    if (tid == 0) {
        int roots = 0;
        #pragma unroll
        for (int w = 0; w < LBL_THREADS / 64; ++w) roots += wsum[w];
        long long total = 2LL * (long long)total_lower + (long long)counters[1];
        long long n_edges_i = total >> 1;               // exact integer // 2
        double n_comp = (double)roots;
        double comp_loss = (n_comp - 1.0) * (n_comp - 1.0);
        double betti = (double)n_edges_i - (double)NN + n_comp;
        double cyc = betti > 0.0 ? betti : 0.0;
        out[0] = (float)(comp_loss + cyc * cyc);
    }
}

extern "C" void kernel_launch(void* const* d_in, const int* in_sizes, int n_in,
                              void* d_out, int out_size, void* d_ws, size_t ws_size,
                              hipStream_t stream) {
    const float* adj = (const float*)d_in[0];
    int* ws = (int*)d_ws;
    int* counters = ws;                       // [0]=lower edges, [1]=diag
    unsigned int* ebuf = (unsigned int*)(ws + 2);
    long long cap_ll = (long long)(ws_size / 4) - 2;
    int cap = cap_ll > 0x7fffffff ? 0x7fffffff : (cap_ll < 0 ? 0 : (int)cap_ll);
    float* out = (float*)d_out;

    init_kernel<<<1, 64, 0, stream>>>(counters);
    scan_kernel<<<NN / 2, 256, 0, stream>>>(adj, counters, ebuf, cap);
    label_final_kernel<<<1, LBL_THREADS, 0, stream>>>(ebuf, counters, cap, out);
}